// Round 3
// baseline (5419.994 us; speedup 1.0000x reference)
//
#include <hip/hip_runtime.h>
#include <cstdint>

#define HH   512
#define HD2  1024
#define HD3  1536
#define VV   32000
#define BB   32
#define LLn  64
#define TT   32
#define NBSCAN 256

typedef unsigned short u16;
typedef __attribute__((ext_vector_type(8))) short short8;
typedef __attribute__((ext_vector_type(4))) float f32x4;

__device__ __forceinline__ float fast_tanh(float x) {
    float e = __expf(2.f * x);
    return 1.f - 2.f / (e + 1.f);
}
__device__ __forceinline__ float fast_sigmoid(float x) {
    return 1.f / (1.f + __expf(-x));
}
__device__ __forceinline__ u16 f2bf(float x) {
    union { float f; unsigned u; } v; v.f = x;
    unsigned r = v.u + 0x7FFFu + ((v.u >> 16) & 1u);   // RNE
    return (u16)(r >> 16);
}

// ---------------------------------------------------------------------------
// init: enc_h -> bf16, embed gather -> bf16 (zero-padded K 300->320),
// s_cur = prev_s, barrier counters = 0.
// ---------------------------------------------------------------------------
__global__ __launch_bounds__(256) void init_misc(
    const float* __restrict__ enc_h, u16* __restrict__ enc_bf,
    const float* __restrict__ embed, const int* __restrict__ tw,
    u16* __restrict__ A_ge, const float* __restrict__ prev_s,
    float* __restrict__ s_cur, int* __restrict__ bar)
{
    const size_t stride = (size_t)gridDim.x * 256;
    size_t idx = (size_t)blockIdx.x * 256 + threadIdx.x;
    for (size_t i = idx; i < (size_t)2048 * 1024; i += stride)
        enc_bf[i] = f2bf(enc_h[i]);
    for (size_t i = idx; i < (size_t)1024 * 320; i += stride) {
        int row = (int)(i / 320), c = (int)(i - (size_t)row * 320);
        A_ge[i] = (c < 300) ? f2bf(embed[(size_t)tw[row] * 300 + c]) : (u16)0;
    }
    for (size_t i = idx; i < 32 * 512; i += stride)
        s_cur[i] = prev_s[i];
    if (idx == 0) { bar[0] = 0; bar[1] = 0; }
}

// ---------------------------------------------------------------------------
// transp: dst[(j+joff)*ldd + k] = src[k*N + j].  grid (N/32, K/32), block 256.
// ---------------------------------------------------------------------------
__global__ __launch_bounds__(256) void transp(
    const float* __restrict__ src, float* __restrict__ dst,
    int N, int joff, int ldd)
{
    __shared__ float t[32][33];
    const int j0 = blockIdx.x * 32, k0 = blockIdx.y * 32, tid = threadIdx.x;
    const int jx = tid & 31, ky = tid >> 5;
    for (int kk = ky; kk < 32; kk += 8)
        t[kk][jx] = src[(size_t)(k0 + kk) * N + j0 + jx];
    __syncthreads();
    const int kx = tid & 31, jy = tid >> 5;
    for (int jj = jy; jj < 32; jj += 8)
        dst[(size_t)(j0 + jj + joff) * ldd + k0 + kx] = t[kx][jj];
}

// ---------------------------------------------------------------------------
// mfma_nt: C[M x N] (fp32) = A(bf16, row-major lda) @ W(fp32, K x N) + bias.
// Tile 256(M) x 64(N), K chunks of 32 (Kt chunks; W rows >= Klim read as 0).
// grid (N/64, M/256), block 256.
// ---------------------------------------------------------------------------
__global__ __launch_bounds__(256) void mfma_nt(
    const u16* __restrict__ Abf, int lda, const float* __restrict__ W, int N,
    int Klim, int Kt, const float* __restrict__ bias, float* __restrict__ C)
{
    __shared__ u16 a_lds[256 * 40];
    __shared__ u16 b_lds[64 * 40];
    const int nb = blockIdx.x, mb = blockIdx.y, tid = threadIdx.x;
    const int w = tid >> 6, ln = tid & 63;
    const int quad = ln >> 4, lm = ln & 15;
    const int n0 = nb * 64;

    f32x4 acc[4][4];
#pragma unroll
    for (int r = 0; r < 4; r++)
#pragma unroll
        for (int c = 0; c < 4; c++)
            acc[r][c] = (f32x4){0.f, 0.f, 0.f, 0.f};

    for (int kt = 0; kt < Kt; kt++) {
        const int k0 = kt * 32;
        {
            const uint4* src = (const uint4*)(Abf + (size_t)(mb * 256 + tid) * lda + k0);
            uint4 v0 = src[0], v1 = src[1], v2 = src[2], v3 = src[3];
            uint4* dst = (uint4*)(a_lds + tid * 40);
            dst[0] = v0; dst[1] = v1; dst[2] = v2; dst[3] = v3;
        }
        {
            int kr = tid >> 3, c8 = (tid & 7) * 8;
            float4 f0 = {0,0,0,0}, f1 = {0,0,0,0};
            if (k0 + kr < Klim) {
                const float4* wp = (const float4*)(W + (size_t)(k0 + kr) * N + n0 + c8);
                f0 = wp[0]; f1 = wp[1];
            }
            u16 u[8] = { f2bf(f0.x), f2bf(f0.y), f2bf(f0.z), f2bf(f0.w),
                         f2bf(f1.x), f2bf(f1.y), f2bf(f1.z), f2bf(f1.w) };
#pragma unroll
            for (int j = 0; j < 8; j++)
                b_lds[(c8 + j) * 40 + kr] = u[j];
        }
        __syncthreads();
        short8 af[4], bfr[4];
#pragma unroll
        for (int r = 0; r < 4; r++)
            af[r] = *(const short8*)(a_lds + ((w * 4 + r) * 16 + lm) * 40 + quad * 8);
#pragma unroll
        for (int c = 0; c < 4; c++)
            bfr[c] = *(const short8*)(b_lds + (c * 16 + lm) * 40 + quad * 8);
#pragma unroll
        for (int r = 0; r < 4; r++)
#pragma unroll
            for (int c = 0; c < 4; c++)
                acc[r][c] = __builtin_amdgcn_mfma_f32_16x16x32_bf16(
                    af[r], bfr[c], acc[r][c], 0, 0, 0);
        __syncthreads();
    }
#pragma unroll
    for (int r = 0; r < 4; r++) {
        int row = mb * 256 + (w * 4 + r) * 16 + quad * 4;
#pragma unroll
        for (int c = 0; c < 4; c++) {
            int col = n0 + c * 16 + lm;
            float bo = bias[col];
#pragma unroll
            for (int q = 0; q < 4; q++)
                C[(size_t)(row + q) * N + col] = acc[r][c][q] + bo;
        }
    }
}

// ---------------------------------------------------------------------------
// grid barrier (all NBSCAN blocks co-resident; agent-scope atomics)
// ---------------------------------------------------------------------------
__device__ __forceinline__ void gbar(int* bar) {
    __syncthreads();
    if (threadIdx.x == 0) {
        __threadfence();
        int g = __hip_atomic_load(&bar[1], __ATOMIC_RELAXED, __HIP_MEMORY_SCOPE_AGENT);
        int v = __hip_atomic_fetch_add(&bar[0], 1, __ATOMIC_ACQ_REL, __HIP_MEMORY_SCOPE_AGENT);
        if (v == NBSCAN - 1) {
            __hip_atomic_store(&bar[0], 0, __ATOMIC_RELAXED, __HIP_MEMORY_SCOPE_AGENT);
            __hip_atomic_fetch_add(&bar[1], 1, __ATOMIC_RELEASE, __HIP_MEMORY_SCOPE_AGENT);
        } else {
            while (__hip_atomic_load(&bar[1], __ATOMIC_ACQUIRE, __HIP_MEMORY_SCOPE_AGENT) == g)
                __builtin_amdgcn_s_sleep(1);
        }
        __threadfence();
    }
    __syncthreads();
}

// ---------------------------------------------------------------------------
// Persistent scan kernel: 256 blocks x 256 threads, whole T=32 recurrence.
// Phase A: tmp1[b][0:1536] = s @ [W_a | W_hzr]          (256 blocks x 6 cols)
// Phase B: scores/softmax (replicated 8x per b), gc+gates in 64-col strips
// Phase C: tmp2 = rs @ W_hs fused with s-update + sseq   (64 blocks x 8 cols)
// ---------------------------------------------------------------------------
__global__ __launch_bounds__(256, 2) void scan_kernel(
    const float* __restrict__ W1t, const float* __restrict__ Whst,
    const float* __restrict__ Uh, const float* __restrict__ Gc,
    const float* __restrict__ Ge, const float* __restrict__ b_a,
    const float* __restrict__ v_w, const float* __restrict__ v_b,
    const float* __restrict__ b_hzr, const float* __restrict__ b_hs,
    float* __restrict__ s_cur, float* __restrict__ tmp1,
    float* __restrict__ rs, float* __restrict__ zbuf, float* __restrict__ pst,
    u16* __restrict__ sseq, int* __restrict__ bar)
{
    __shared__ float big[32 * 516];       // 66 KB: s or rs, [b][k] stride 516
    __shared__ float outs[HH];
    __shared__ float sc_red[64 * 4];
    __shared__ float attnv[LLn];
    __shared__ float gcp[3 * 64 * 4];
    __shared__ float gcs[3 * 64];
    const int p = blockIdx.x, tid = threadIdx.x;

    for (int t = 0; t < TT; t++) {
        // ---------------- phase A: tmp1 = s @ W1 ----------------
        {
            for (int i = tid; i < 32 * 128; i += 256) {
                int b = i >> 7, k4 = (i & 127) << 2;
                float4 v = *(const float4*)(s_cur + b * HH + k4);
                *(float4*)(big + b * 516 + k4) = v;
            }
            __syncthreads();
            const int jj = tid >> 5, b = tid & 31;
            if (jj < 6) {
                const int j = p * 6 + jj;
                const float* wr = W1t + (size_t)j * HH;
                const float* sr = big + b * 516;
                float a0 = 0.f, a1 = 0.f, a2 = 0.f, a3 = 0.f;
                for (int k = 0; k < HH; k += 4) {
                    float4 wv = *(const float4*)(wr + k);
                    float4 sv = *(const float4*)(sr + k);
                    a0 = fmaf(sv.x, wv.x, a0);
                    a1 = fmaf(sv.y, wv.y, a1);
                    a2 = fmaf(sv.z, wv.z, a2);
                    a3 = fmaf(sv.w, wv.w, a3);
                }
                tmp1[b * HD3 + j] = (a0 + a1) + (a2 + a3);
            }
        }
        gbar(bar);
        // ---------------- phase B: attention + gates ----------------
        {
            const int b = p >> 3, sub = p & 7;
            for (int i = tid; i < HH; i += 256)
                outs[i] = tmp1[b * HD3 + i] + b_a[i];
            __syncthreads();
            {   // scores: each thread 128 k of one l
                const int l = tid >> 2, kq = tid & 3;
                const float* uh = Uh + ((size_t)b * LLn + l) * HH + kq * 128;
                const float* os = outs + kq * 128;
                const float* vw = v_w + kq * 128;
                float a = 0.f;
                for (int k = 0; k < 128; k += 4) {
                    float4 u = *(const float4*)(uh + k);
                    float4 o = *(const float4*)(os + k);
                    float4 w = *(const float4*)(vw + k);
                    a = fmaf(fast_tanh(o.x + u.x), w.x, a);
                    a = fmaf(fast_tanh(o.y + u.y), w.y, a);
                    a = fmaf(fast_tanh(o.z + u.z), w.z, a);
                    a = fmaf(fast_tanh(o.w + u.w), w.w, a);
                }
                sc_red[tid] = a;
            }
            __syncthreads();
            if (tid < 64) {
                const float* q = sc_red + tid * 4;
                float v = q[0] + q[1] + q[2] + q[3] + v_b[0];
                float m = v;
                for (int o = 32; o > 0; o >>= 1) m = fmaxf(m, __shfl_xor(m, o));
                float e = __expf(v - m);
                float ssum = e;
                for (int o = 32; o > 0; o >>= 1) ssum += __shfl_xor(ssum, o);
                attnv[tid] = e / ssum;
            }
            __syncthreads();
            {   // gc strips: cols sub*64..+64 in each of the 3 gate segments
                const int cl = tid & 63, lq = tid >> 6;
#pragma unroll
                for (int seg = 0; seg < 3; seg++) {
                    const int col = seg * HH + sub * 64 + cl;
                    const float* g = Gc + ((size_t)b * LLn + lq * 16) * HD3 + col;
                    float a = 0.f;
#pragma unroll
                    for (int l = 0; l < 16; l++)
                        a = fmaf(attnv[lq * 16 + l], g[(size_t)l * HD3], a);
                    gcp[(seg * 64 + cl) * 4 + lq] = a;
                }
            }
            __syncthreads();
            if (tid < 192) {
                const float* q = gcp + tid * 4;
                gcs[tid] = (q[0] + q[1]) + (q[2] + q[3]);
            }
            __syncthreads();
            if (tid < 64) {
                const int j = sub * 64 + tid;
                const float* ge = Ge + ((size_t)b * TT + t) * HD3;
                float gz = ge[j] + tmp1[b * HD3 + HH + j] + b_hzr[j] + gcs[tid];
                float gr = ge[HH + j] + tmp1[b * HD3 + HD2 + j] + b_hzr[HH + j] + gcs[64 + tid];
                float z = fast_sigmoid(gz);
                float r = fast_sigmoid(gr);
                float sv = s_cur[b * HH + j];
                rs[b * HH + j]   = r * sv;
                zbuf[b * HH + j] = z;
                pst[b * HH + j]  = ge[HD2 + j] + gcs[128 + tid] + b_hs[j];
            }
        }
        gbar(bar);
        // ---------------- phase C: tmp2 + s update (blocks 0..63) ----------------
        if (p < 64) {
            for (int i = tid; i < 32 * 128; i += 256) {
                int b = i >> 7, k4 = (i & 127) << 2;
                float4 v = *(const float4*)(rs + b * HH + k4);
                *(float4*)(big + b * 516 + k4) = v;
            }
            __syncthreads();
            const int jj = tid >> 5, b = tid & 31;
            const int j = p * 8 + jj;
            const float* wr = Whst + (size_t)j * HH;
            const float* rr = big + b * 516;
            float a0 = 0.f, a1 = 0.f, a2 = 0.f, a3 = 0.f;
            for (int k = 0; k < HH; k += 4) {
                float4 wv = *(const float4*)(wr + k);
                float4 rv = *(const float4*)(rr + k);
                a0 = fmaf(rv.x, wv.x, a0);
                a1 = fmaf(rv.y, wv.y, a1);
                a2 = fmaf(rv.z, wv.z, a2);
                a3 = fmaf(rv.w, wv.w, a3);
            }
            float dot = (a0 + a1) + (a2 + a3);
            float st = fast_tanh(pst[b * HH + j] + dot);
            float z  = zbuf[b * HH + j];
            float so = s_cur[b * HH + j];
            float sn = fmaf(z, st - so, so);
            s_cur[b * HH + j] = sn;
            sseq[((size_t)b * TT + t) * HH + j] = f2bf(sn);
        }
        gbar(bar);
    }
}

// ---------------------------------------------------------------------------
extern "C" void kernel_launch(void* const* d_in, const int* in_sizes, int n_in,
                              void* d_out, int out_size, void* d_ws, size_t ws_size,
                              hipStream_t stream)
{
    const float* enc_h  = (const float*)d_in[0];
    const float* prev_s = (const float*)d_in[1];
    const int*   tw     = (const int*)  d_in[2];
    const float* embed  = (const float*)d_in[3];
    const float* W_a    = (const float*)d_in[4];
    const float* b_a    = (const float*)d_in[5];
    const float* U_a    = (const float*)d_in[6];
    const float* b_Ua   = (const float*)d_in[7];
    const float* v_w    = (const float*)d_in[8];
    const float* v_b    = (const float*)d_in[9];
    const float* W_emb  = (const float*)d_in[10];
    const float* b_emb  = (const float*)d_in[11];
    const float* W_hzr  = (const float*)d_in[12];
    const float* b_hzr  = (const float*)d_in[13];
    const float* W_hs   = (const float*)d_in[14];
    const float* b_hs   = (const float*)d_in[15];
    const float* W_ctx  = (const float*)d_in[16];
    const float* b_ctx  = (const float*)d_in[17];
    const float* W_out  = (const float*)d_in[18];
    const float* b_out  = (const float*)d_in[19];
    float* out = (float*)d_out;

    char* wsb = (char*)d_ws;
    float* Uh    = (float*)wsb;  wsb += (size_t)2048 * 512 * 4;
    float* Gc    = (float*)wsb;  wsb += (size_t)2048 * 1536 * 4;
    float* Ge    = (float*)wsb;  wsb += (size_t)1024 * 1536 * 4;
    float* W1t   = (float*)wsb;  wsb += (size_t)1536 * 512 * 4;
    float* Whst  = (float*)wsb;  wsb += (size_t)512 * 512 * 4;
    float* tmp1  = (float*)wsb;  wsb += (size_t)32 * 1536 * 4;
    float* s_cur = (float*)wsb;  wsb += 32 * 512 * 4;
    float* rs    = (float*)wsb;  wsb += 32 * 512 * 4;
    float* zbuf  = (float*)wsb;  wsb += 32 * 512 * 4;
    float* pst   = (float*)wsb;  wsb += 32 * 512 * 4;
    u16* enc_bf  = (u16*)wsb;    wsb += (size_t)2048 * 1024 * 2;
    u16* A_ge    = (u16*)wsb;    wsb += (size_t)1024 * 320 * 2;
    u16* sseq    = (u16*)wsb;    wsb += (size_t)1024 * 512 * 2;
    int* bar     = (int*)wsb;    wsb += 256;

    init_misc<<<2048, 256, 0, stream>>>(enc_h, enc_bf, embed, tw, A_ge,
                                        prev_s, s_cur, bar);
    transp<<<dim3(16, 16), 256, 0, stream>>>(W_a,   W1t,  512,  0,   512);
    transp<<<dim3(32, 16), 256, 0, stream>>>(W_hzr, W1t,  1024, 512, 512);
    transp<<<dim3(16, 16), 256, 0, stream>>>(W_hs,  Whst, 512,  0,   512);

    mfma_nt<<<dim3(8, 8),   256, 0, stream>>>(enc_bf, 1024, U_a,   512,  1024, 32, b_Ua,  Uh);
    mfma_nt<<<dim3(24, 8),  256, 0, stream>>>(enc_bf, 1024, W_ctx, 1536, 1024, 32, b_ctx, Gc);
    mfma_nt<<<dim3(24, 4),  256, 0, stream>>>(A_ge,   320,  W_emb, 1536, 300,  10, b_emb, Ge);

    scan_kernel<<<NBSCAN, 256, 0, stream>>>(W1t, Whst, Uh, Gc, Ge, b_a, v_w, v_b,
                                            b_hzr, b_hs, s_cur, tmp1, rs, zbuf,
                                            pst, sseq, bar);

    mfma_nt<<<dim3(500, 4), 256, 0, stream>>>(sseq, 512, W_out, 32000, 512, 16, b_out, out);
}